// Round 19
// baseline (146.270 us; speedup 1.0000x reference)
//
#include <hip/hip_runtime.h>
#include <math.h>

#define Bb 2
#define Ss 128
#define Hh 768
#define Cc 5
#define Mm 256       // Bb*Ss
#define NEGV -1024.0f
#define SCALE 2.8853900817779268f   // 2/ln(2): Ep*Ea = e^{2x}

// haT8: fp8-e4m3 [b][c][h16][a][h&15], h16=h>>4 in [0,48)
// byte index = ((b*5+c)*48 + h16)*2048 + a*16 + (h&15)
#define PT 2
#define NBLK (Mm / PT * Cc)   // 640

typedef __attribute__((ext_vector_type(8))) short bf16x8;
typedef __attribute__((ext_vector_type(4))) float f32x4;
typedef __attribute__((ext_vector_type(2))) float f32x2;
typedef unsigned short ushort;
typedef unsigned char uchar;

__device__ __forceinline__ unsigned pack_hi16(float hi, float lo) {
    return (__float_as_uint(hi) & 0xFFFF0000u) | (__float_as_uint(lo) >> 16);
}
__device__ __forceinline__ bf16x8 pack_bf16x8(float4 lo, float4 hi) {
    union { bf16x8 v; unsigned u[4]; } r;
    r.u[0] = pack_hi16(lo.y, lo.x);
    r.u[1] = pack_hi16(lo.w, lo.z);
    r.u[2] = pack_hi16(hi.y, hi.x);
    r.u[3] = pack_hi16(hi.w, hi.z);
    return r.v;
}
__device__ __forceinline__ uchar to_fp8(float v) {
    return (uchar)(__builtin_amdgcn_cvt_pk_fp8_f32(v, v, 0, false) & 0xFF);
}

#define SB __builtin_amdgcn_sched_barrier(0);

// ---------------- Kernel 1: LDS-staged bf16 MFMA GEMM; Ep=exp2(hp') fp32, ha fp8 ----------------
__global__ __launch_bounds__(256)
void gemm_mfma(const float* __restrict__ X,
               const float* __restrict__ Wprd,
               const float* __restrict__ Warg,
               const float* __restrict__ bprd,
               const float* __restrict__ barg,
               float* __restrict__ EpG,
               uchar* __restrict__ haT8,
               float* __restrict__ accum)
{
    __shared__ __align__(16) ushort Asb[64][40];
    __shared__ __align__(16) ushort Bsb[32][40];

    if (blockIdx.x == 0 && blockIdx.y == 0 && threadIdx.x == 0) {
        accum[0] = 0.f; accum[1] = 0.f;
        ((unsigned*)accum)[2] = 0u;      // completion counter
    }
    const int bm   = blockIdx.x;          // 0..3   (64 rows)
    const int bn   = blockIdx.y;          // 0..143 (32 cols)
    const int tid  = threadIdx.x;
    const int wave = tid >> 6;
    const int lane = tid & 63;
    const int l16  = lane & 15;
    const int quad = lane >> 4;

    const float* Wsrc; const float* bsrc;
    const int nb = bn * 32;
    if (nb < Hh) { Wsrc = Wprd + (size_t)nb * Hh;        bsrc = bprd + nb; }
    else         { Wsrc = Warg + (size_t)(nb - Hh) * Hh; bsrc = barg + (nb - Hh); }

    const int srow = tid >> 2;
    const int sko  = (tid & 3) * 8;
    const float* gA = X + (size_t)(bm * 64 + srow) * Hh + sko;
    const float* gB = Wsrc + (size_t)(tid >> 2) * Hh + sko;   // valid for tid<128

    float4 pa0 = *(const float4*)(gA);
    float4 pa1 = *(const float4*)(gA + 4);
    float4 pb0, pb1;
    if (tid < 128) { pb0 = *(const float4*)(gB); pb1 = *(const float4*)(gB + 4); }

    f32x4 acc0 = {0.f,0.f,0.f,0.f}, acc1 = {0.f,0.f,0.f,0.f};

    for (int k0 = 0; k0 < Hh; k0 += 32) {
        *(bf16x8*)&Asb[srow][sko] = pack_bf16x8(pa0, pa1);
        if (tid < 128) *(bf16x8*)&Bsb[tid >> 2][sko] = pack_bf16x8(pb0, pb1);
        __syncthreads();
        const int kn = k0 + 32;
        if (kn < Hh) {
            pa0 = *(const float4*)(gA + kn);
            pa1 = *(const float4*)(gA + kn + 4);
            if (tid < 128) { pb0 = *(const float4*)(gB + kn); pb1 = *(const float4*)(gB + kn + 4); }
        }
        bf16x8 af = *(const bf16x8*)&Asb[wave * 16 + l16][quad * 8];
        bf16x8 b0 = *(const bf16x8*)&Bsb[l16][quad * 8];
        bf16x8 b1 = *(const bf16x8*)&Bsb[16 + l16][quad * 8];
        acc0 = __builtin_amdgcn_mfma_f32_16x16x32_bf16(af, b0, acc0, 0, 0, 0);
        acc1 = __builtin_amdgcn_mfma_f32_16x16x32_bf16(af, b1, acc1, 0, 0, 0);
        __syncthreads();
    }

    const float sb0 = SCALE * bsrc[l16];
    const float sb1 = SCALE * bsrc[16 + l16];
    const int row = bm * 64 + wave * 16 + quad * 4;

    if (nb < Hh) {   // Ep: row-major fp32 [m][h] = exp2(hp')
        #pragma unroll
        for (int r = 0; r < 4; ++r) {
            const int mm = row + r;
            EpG[(size_t)mm * Hh + nb + l16]      = __builtin_amdgcn_exp2f(SCALE * acc0[r] + sb0);
            EpG[(size_t)mm * Hh + nb + 16 + l16] = __builtin_amdgcn_exp2f(SCALE * acc1[r] + sb1);
        }
    } else {         // ha -> haT8 fp8 [b][c][h>>4][a][h&15]
        const int q  = nb - Hh;
        const int cU = q / Hh;
        const int h0 = q % Hh;                 // multiple of 32
        #pragma unroll
        for (int r = 0; r < 4; ++r) {
            const int mm = row + r;
            const int bI = mm >> 7, aI = mm & 127;
            const size_t base = ((size_t)(bI * Cc + cU) * 48 + (h0 >> 4)) * 2048 + (size_t)aI * 16 + l16;
            haT8[base]        = to_fp8(SCALE * acc0[r] + sb0);   // col h0+l16
            haT8[base + 2048] = to_fp8(SCALE * acc1[r] + sb1);   // col h0+16+l16
        }
    }
}

// ---------------- Kernel 2: biaffine; fp8 ha stream (16 h per dwordx4), factorized exp2 ----------------
// Grid 640 = (p-tile, c), 512 thr: tid = hq*128 + a. term = w * rcp(Ep*Ea + 1), Ea shared over p.
#define LOADG4(R, g) \
    R##0 = hap4[((g)*4+0)*128]; R##1 = hap4[((g)*4+1)*128]; \
    R##2 = hap4[((g)*4+2)*128]; R##3 = hap4[((g)*4+3)*128];

#define HALF8(dA, dB, dC, dD, off) { \
    const float e0 = __builtin_amdgcn_exp2f(dA[0]); \
    const float e1 = __builtin_amdgcn_exp2f(dA[1]); \
    const float e2 = __builtin_amdgcn_exp2f(dB[0]); \
    const float e3 = __builtin_amdgcn_exp2f(dB[1]); \
    const float e4 = __builtin_amdgcn_exp2f(dC[0]); \
    const float e5 = __builtin_amdgcn_exp2f(dC[1]); \
    const float e6 = __builtin_amdgcn_exp2f(dD[0]); \
    const float e7 = __builtin_amdgcn_exp2f(dD[1]); \
    float r; \
    r = __builtin_amdgcn_rcpf(fmaf(q0v[(off)+0], e0, 1.0f)); ac00 = fmaf(w16[(off)+0], r, ac00); \
    r = __builtin_amdgcn_rcpf(fmaf(q0v[(off)+1], e1, 1.0f)); ac01 = fmaf(w16[(off)+1], r, ac01); \
    r = __builtin_amdgcn_rcpf(fmaf(q0v[(off)+2], e2, 1.0f)); ac00 = fmaf(w16[(off)+2], r, ac00); \
    r = __builtin_amdgcn_rcpf(fmaf(q0v[(off)+3], e3, 1.0f)); ac01 = fmaf(w16[(off)+3], r, ac01); \
    r = __builtin_amdgcn_rcpf(fmaf(q0v[(off)+4], e4, 1.0f)); ac00 = fmaf(w16[(off)+4], r, ac00); \
    r = __builtin_amdgcn_rcpf(fmaf(q0v[(off)+5], e5, 1.0f)); ac01 = fmaf(w16[(off)+5], r, ac01); \
    r = __builtin_amdgcn_rcpf(fmaf(q0v[(off)+6], e6, 1.0f)); ac00 = fmaf(w16[(off)+6], r, ac00); \
    r = __builtin_amdgcn_rcpf(fmaf(q0v[(off)+7], e7, 1.0f)); ac01 = fmaf(w16[(off)+7], r, ac01); \
    r = __builtin_amdgcn_rcpf(fmaf(q1v[(off)+0], e0, 1.0f)); ac10 = fmaf(w16[(off)+0], r, ac10); \
    r = __builtin_amdgcn_rcpf(fmaf(q1v[(off)+1], e1, 1.0f)); ac11 = fmaf(w16[(off)+1], r, ac11); \
    r = __builtin_amdgcn_rcpf(fmaf(q1v[(off)+2], e2, 1.0f)); ac10 = fmaf(w16[(off)+2], r, ac10); \
    r = __builtin_amdgcn_rcpf(fmaf(q1v[(off)+3], e3, 1.0f)); ac11 = fmaf(w16[(off)+3], r, ac11); \
    r = __builtin_amdgcn_rcpf(fmaf(q1v[(off)+4], e4, 1.0f)); ac10 = fmaf(w16[(off)+4], r, ac10); \
    r = __builtin_amdgcn_rcpf(fmaf(q1v[(off)+5], e5, 1.0f)); ac11 = fmaf(w16[(off)+5], r, ac11); \
    r = __builtin_amdgcn_rcpf(fmaf(q1v[(off)+6], e6, 1.0f)); ac10 = fmaf(w16[(off)+6], r, ac10); \
    r = __builtin_amdgcn_rcpf(fmaf(q1v[(off)+7], e7, 1.0f)); ac11 = fmaf(w16[(off)+7], r, ac11); \
}

#define C1(u, hx) { \
    float w16[16], q0v[16], q1v[16]; \
    _Pragma("unroll") \
    for (int z = 0; z < 16; ++z) { \
        w16[z] = wrow[(hx) + z]; q0v[z] = ep0[(hx) + z]; q1v[z] = ep1[(hx) + z]; \
    } \
    f32x2 d0 = __builtin_amdgcn_cvt_pk_f32_fp8((u).x, false); \
    f32x2 d1 = __builtin_amdgcn_cvt_pk_f32_fp8((u).x, true); \
    f32x2 d2 = __builtin_amdgcn_cvt_pk_f32_fp8((u).y, false); \
    f32x2 d3 = __builtin_amdgcn_cvt_pk_f32_fp8((u).y, true); \
    f32x2 d4 = __builtin_amdgcn_cvt_pk_f32_fp8((u).z, false); \
    f32x2 d5 = __builtin_amdgcn_cvt_pk_f32_fp8((u).z, true); \
    f32x2 d6 = __builtin_amdgcn_cvt_pk_f32_fp8((u).w, false); \
    f32x2 d7 = __builtin_amdgcn_cvt_pk_f32_fp8((u).w, true); \
    HALF8(d0, d1, d2, d3, 0) \
    HALF8(d4, d5, d6, d7, 8) \
}

#define CONSUMEG4(R, g) \
    C1(R##0, hbase + ((g)*4+0)*16)  C1(R##1, hbase + ((g)*4+1)*16) \
    C1(R##2, hbase + ((g)*4+2)*16)  C1(R##3, hbase + ((g)*4+3)*16)

__global__ __launch_bounds__(512, 6)
void biaffine_loss(const float* __restrict__ EpG,
                   const uchar* __restrict__ haT8,
                   const float* __restrict__ Wout,
                   const int* __restrict__ ng,
                   const int* __restrict__ att,
                   const float* __restrict__ target,
                   float* __restrict__ out_logits,
                   float* __restrict__ accum,
                   float* __restrict__ out_loss)
{
    __shared__ float partial[PT][3][Ss];
    __shared__ float maskneg[PT][Ss];
    __shared__ float redmax[PT][2];
    __shared__ float red3[PT][2][3];
    __shared__ float swr_s;

    const int pt  = blockIdx.x / Cc;     // 0..127
    const int c   = blockIdx.x - pt * Cc;
    const int bp0 = pt * PT;
    const int b   = bp0 >> 7;
    const int tid = threadIdx.x;
    const int a   = tid & (Ss - 1);
    const int hq  = __builtin_amdgcn_readfirstlane(tid >> 7);   // 0..3, forced SGPR
    const int lane = tid & 63;

    // uniform base pointers for scalar loads
    const float* wrow = Wout + (size_t)c * Hh;
    const float* ep0  = EpG + (size_t)(bp0 + 0) * Hh;
    const float* ep1  = EpG + (size_t)(bp0 + 1) * Hh;

    if (tid < PT * Ss) {   // mask staging
        const int p_i = tid >> 7;
        const int aa  = tid & (Ss - 1);
        int any = 0;
        if (att[b * Ss + aa] > 0) {
            const int* ngp = ng + (size_t)(bp0 + p_i) * Cc * Ss + aa;
            #pragma unroll
            for (int cc = 0; cc < Cc; ++cc) any |= ngp[cc * Ss];
        }
        maskneg[p_i][aa] = any ? 0.0f : NEGV;
    }

    if (tid < 64) {    // wave 0: sumW[c] from global (coalesced)
        float s = 0.f;
        #pragma unroll
        for (int i = 0; i < Hh / 64; ++i) s += wrow[tid + i * 64];
        #pragma unroll
        for (int off = 32; off; off >>= 1) s += __shfl_xor(s, off, 64);
        if (tid == 0) swr_s = s;
    }

    // thread's ha stream: uint4 j = 16 fp8 h values; index = (hq*12 + j)*128 + a
    const uint4* hap4 = (const uint4*)(haT8 + ((size_t)(b * Cc + c) * 48) * 2048)
                      + (size_t)hq * 12 * 128 + a;
    const int hbase = hq * 192;

    uint4 A0, A1, A2, A3;
    uint4 B0, B1, B2, B3;
    float ac00 = 0.f, ac01 = 0.f, ac10 = 0.f, ac11 = 0.f;

    LOADG4(A, 0) SB
    LOADG4(B, 1) SB  CONSUMEG4(A, 0) SB
    LOADG4(A, 2) SB  CONSUMEG4(B, 1) SB
    CONSUMEG4(A, 2)

    if (hq != 0) {
        partial[0][hq - 1][a] = ac00 + ac01;
        partial[1][hq - 1][a] = ac10 + ac11;
    }
    __syncthreads();

    float logit[PT];
    const int wv = tid >> 6;             // 0/1 for hq==0 threads
    if (hq == 0) {
        const float ps[PT] = { ac00 + ac01, ac10 + ac11 };
        #pragma unroll
        for (int p = 0; p < PT; ++p) {
            const float full = ps[p] + partial[p][0][a] + partial[p][1][a] + partial[p][2][a];
            logit[p] = swr_s - 2.0f * full + maskneg[p][a];
            out_logits[((size_t)(bp0 + p) * Cc + c) * Ss + a] = logit[p];
            float mx = logit[p];
            #pragma unroll
            for (int off = 32; off; off >>= 1) mx = fmaxf(mx, __shfl_xor(mx, off, 64));
            if (lane == 0) redmax[p][wv] = mx;
        }
    }
    __syncthreads();

    if (hq == 0) {
        #pragma unroll
        for (int p = 0; p < PT; ++p) {
            const float rm = fmaxf(redmax[p][0], redmax[p][1]);
            const float e  = __builtin_amdgcn_exp2f((logit[p] - rm) * 1.4426950408889634f);
            const float tg = target[((size_t)(bp0 + p) * Cc + c) * Ss + a];
            float se = e, st = tg, sx = tg * logit[p];
            #pragma unroll
            for (int off = 32; off; off >>= 1) {
                se += __shfl_xor(se, off, 64);
                st += __shfl_xor(st, off, 64);
                sx += __shfl_xor(sx, off, 64);
            }
            if (lane == 0) { red3[p][wv][0] = se; red3[p][wv][1] = st; red3[p][wv][2] = sx; }
        }
    }
    __syncthreads();

    if (tid == 0) {
        float nsum = 0.f, dsum = 0.f;
        #pragma unroll
        for (int p = 0; p < PT; ++p) {
            const float rm = fmaxf(redmax[p][0], redmax[p][1]);
            const float SE = red3[p][0][0] + red3[p][1][0];
            const float ST = red3[p][0][1] + red3[p][1][1];
            const float SX = red3[p][0][2] + red3[p][1][2];
            const float lse = rm + __builtin_amdgcn_logf(SE) * 0.6931471805599453f;
            nsum += lse * ST - SX;
            dsum += ST;
        }
        atomicAdd(&accum[0], nsum);
        atomicAdd(&accum[1], dsum);
        __threadfence();
        const unsigned old = atomicAdd((unsigned*)(accum + 2), 1u);
        if (old == (unsigned)(NBLK - 1)) {          // last block: finalize loss
            const float n = atomicAdd(&accum[0], 0.0f);
            const float d = atomicAdd(&accum[1], 0.0f);
            out_loss[0] = n / d;
        }
    }
}

extern "C" void kernel_launch(void* const* d_in, const int* in_sizes, int n_in,
                              void* d_out, int out_size, void* d_ws, size_t ws_size,
                              hipStream_t stream) {
    const float* seq    = (const float*)d_in[0];
    const int*   att    = (const int*)  d_in[1];
    const int*   ng     = (const int*)  d_in[2];
    const float* target = (const float*)d_in[3];
    const float* Wprd   = (const float*)d_in[4];
    const float* bprd   = (const float*)d_in[5];
    const float* Warg   = (const float*)d_in[6];
    const float* barg   = (const float*)d_in[7];
    const float* Wout   = (const float*)d_in[8];

    float* out    = (float*)d_out;
    float* EpG    = (float*)d_ws;                        // 196608 floats
    uchar* haT8   = (uchar*)(EpG + 196608);              // 983040 bytes
    float* accum  = EpG + 196608 + 245760;               // 3 slots

    gemm_mfma<<<dim3(4, 144), 256, 0, stream>>>(seq, Wprd, Warg, bprd, barg,
                                                EpG, haT8, accum);
    biaffine_loss<<<dim3(NBLK), 512, 0, stream>>>(EpG, haT8, Wout, ng, att, target,
                                                  out + 1, accum, out);
}